// Round 10
// baseline (33.710 us; speedup 1.0000x reference)
//
#include <hip/hip_runtime.h>

#define Hd    256
#define OUTD  10
#define DDEP  10
#define KSTR  12
#define TLEN  8192
#define NTHR  512
#define NBLK  256
#define TILE  2048

// Module-scope sync: zero-init at load, monotonic across replays.
// g_ticket: consumer arrivals (255/replay) -> gen = ticket/255.
// g_flag:   K publications (1/replay) -> wait for flag >= gen+1.
__device__ unsigned g_ticket, g_flag;

__device__ __forceinline__ int ph(int j) { return j + (j >> 5); }

// LDS floats: yb[22528] transpose buf (block0 reuses first 5120 as W3s+Vs),
// Ks @22528 (128), xs @22656 (2058 logical, swizzled).
#define OFF_KS  22528
#define OFF_XS  (OFF_KS + 128)
#define XS_LOG  (TILE + DDEP)
#define SMEM_FLOATS (OFF_XS + XS_LOG + (XS_LOG >> 5) + 8)   // ~99 KB

__global__ __launch_bounds__(NTHR, 1) void fused_rnn_kernel(
    const float* __restrict__ x, const float* __restrict__ w1g,
    const float* __restrict__ W2, const float* __restrict__ W3,
    float* __restrict__ y, float* __restrict__ Kb)
{
    __shared__ float smem[SMEM_FLOATS];
    __shared__ unsigned sgen;
    float* yb = smem;
    float* Ks = smem + OFF_KS;
    float* xs = smem + OFF_XS;

    const int tid = threadIdx.x;
    const int bid = blockIdx.x;
    const int b   = bid >> 2;
    const int t0  = (bid & 3) * TILE;
    const float* xb = x + b * TLEN;

    if (bid == 0) {
        // ---------------- producer: lean register-resident chain ----------------
        float* W3s = yb;                   // [10*256]
        float* Vs  = yb + 2560;            // [DDEP][256]
        const int rp = tid >> 2, q = tid & 3;   // rows {2rp,2rp+1}, col quarter q

        // W2 chunk -> registers. launch_bounds(512,1) gives ~512-reg budget so
        // these 128 VGPRs stay RESIDENT (r5-r9 were silently re-loading from
        // global every iteration under a 128-reg occupancy cap).
        const float4* W2v = (const float4*)W2;
        float4 A0[16], A1[16];
        #pragma unroll
        for (int k = 0; k < 16; ++k) {
            const int m = (k + 4 * q) & 15;
            A0[k] = W2v[(2 * rp) * 64 + q * 16 + m];
            A1[k] = W2v[(2 * rp + 1) * 64 + q * 16 + m];
        }

        for (int i = tid; i < OUTD * Hd; i += NTHR) W3s[i] = W3[i];
        if (tid < Hd) Vs[tid] = w1g[tid];
        for (int j = tid; j < XS_LOG; j += NTHR) {        // own conv tile (tile 0)
            const int g = t0 - DDEP + j;
            xs[ph(j)] = (g >= 0) ? xb[g] : 0.0f;
        }
        __syncthreads();

        // chain: v_{d+1} = W2 * v_d  (9 serial iterations, LDS+VALU only)
        #pragma unroll 1
        for (int d = 0; d < DDEP - 1; ++d) {
            const float4* vsrc = (const float4*)(Vs + d * Hd);
            float4 a0 = make_float4(0.f, 0.f, 0.f, 0.f);
            float4 a1 = make_float4(0.f, 0.f, 0.f, 0.f);
            #pragma unroll
            for (int k = 0; k < 16; ++k) {
                const float4 vv = vsrc[q * 16 + ((k + 4 * q) & 15)];
                a0.x = fmaf(A0[k].x, vv.x, a0.x);
                a0.y = fmaf(A0[k].y, vv.y, a0.y);
                a0.z = fmaf(A0[k].z, vv.z, a0.z);
                a0.w = fmaf(A0[k].w, vv.w, a0.w);
                a1.x = fmaf(A1[k].x, vv.x, a1.x);
                a1.y = fmaf(A1[k].y, vv.y, a1.y);
                a1.z = fmaf(A1[k].z, vv.z, a1.z);
                a1.w = fmaf(A1[k].w, vv.w, a1.w);
            }
            float p0 = (a0.x + a0.y) + (a0.z + a0.w);
            float p1 = (a1.x + a1.y) + (a1.z + a1.w);
            p0 += __shfl_xor(p0, 1);  p0 += __shfl_xor(p0, 2);
            p1 += __shfl_xor(p1, 1);  p1 += __shfl_xor(p1, 2);
            if (q == 0)
                ((float2*)(Vs + (d + 1) * Hd))[rp] = make_float2(p0, p1);
            __syncthreads();
        }

        // K[d][o] = W3[o] . v_d : wave w handles d = w and w+8
        {
            const int w = tid >> 6, l = tid & 63;
            #pragma unroll
            for (int dd = 0; dd < 2; ++dd) {
                const int d = w + dd * 8;
                if (d < DDEP) {
                    const float4 vv = ((const float4*)(Vs + d * Hd))[l];
                    #pragma unroll
                    for (int o = 0; o < OUTD; ++o) {
                        const float4 wv = ((const float4*)(W3s + o * Hd))[l];
                        float p = fmaf(wv.x, vv.x,
                                  fmaf(wv.y, vv.y,
                                  fmaf(wv.z, vv.z, wv.w * vv.w)));
                        p += __shfl_xor(p, 1);  p += __shfl_xor(p, 2);
                        p += __shfl_xor(p, 4);  p += __shfl_xor(p, 8);
                        p += __shfl_xor(p, 16); p += __shfl_xor(p, 32);
                        if (l == 0) Ks[d * KSTR + o] = p;
                    }
                    if (l == 1) { Ks[d * KSTR + 10] = 0.f; Ks[d * KSTR + 11] = 0.f; }
                }
            }
        }
        __syncthreads();
        if (tid < DDEP * KSTR) Kb[tid] = Ks[tid];
        __syncthreads();                    // Kb stores drained before publish
        if (tid == 0) {
            __threadfence();                // release: K visible at coherent point
            __hip_atomic_fetch_add(&g_flag, 1u, __ATOMIC_RELEASE,
                                   __HIP_MEMORY_SCOPE_AGENT);
        }
        // falls through to conv; Ks live in LDS
    } else {
        // ---------------- consumers: stage x, then wait for K ----------------
        if (tid == 0)
            sgen = __hip_atomic_fetch_add(&g_ticket, 1u, __ATOMIC_RELAXED,
                                          __HIP_MEMORY_SCOPE_AGENT) / (NBLK - 1);
        for (int j = tid; j < XS_LOG; j += NTHR) {
            const int g = t0 - DDEP + j;
            xs[ph(j)] = (g >= 0) ? xb[g] : 0.0f;
        }
        __syncthreads();
        if (tid == 0) {
            const unsigned target = sgen + 1u;
            unsigned guard = 0;
            while (__hip_atomic_load(&g_flag, __ATOMIC_RELAXED,
                                     __HIP_MEMORY_SCOPE_AGENT) < target) {
                __builtin_amdgcn_s_sleep(8);
                if (++guard > 4000000u) break;      // fail loud, not hang
            }
            (void)__hip_atomic_load(&g_flag, __ATOMIC_ACQUIRE,
                                    __HIP_MEMORY_SCOPE_AGENT);
        }
        __syncthreads();
        if (tid < DDEP * KSTR) Ks[tid] = Kb[tid];
        __syncthreads();
    }

    // ---------------- causal FIR: 4 consecutive positions per thread ----------------
    const int ub = tid * 4;
    float acc[4][OUTD];
    #pragma unroll
    for (int i = 0; i < 4; ++i)
        #pragma unroll
        for (int o = 0; o < OUTD; ++o) acc[i][o] = 0.0f;

    float wn[4];
    #pragma unroll
    for (int i = 0; i < 4; ++i) wn[i] = xs[ph(ub + DDEP + i)];

    #pragma unroll
    for (int d = 0; d < DDEP; ++d) {
        const float4 kA = *(const float4*)&Ks[d * KSTR];
        const float4 kB = *(const float4*)&Ks[d * KSTR + 4];
        const float2 kC = *(const float2*)&Ks[d * KSTR + 8];
        #pragma unroll
        for (int i = 0; i < 4; ++i) {
            const float xv = wn[i];
            acc[i][0] = fmaf(kA.x, xv, acc[i][0]);
            acc[i][1] = fmaf(kA.y, xv, acc[i][1]);
            acc[i][2] = fmaf(kA.z, xv, acc[i][2]);
            acc[i][3] = fmaf(kA.w, xv, acc[i][3]);
            acc[i][4] = fmaf(kB.x, xv, acc[i][4]);
            acc[i][5] = fmaf(kB.y, xv, acc[i][5]);
            acc[i][6] = fmaf(kB.z, xv, acc[i][6]);
            acc[i][7] = fmaf(kB.w, xv, acc[i][7]);
            acc[i][8] = fmaf(kC.x, xv, acc[i][8]);
            acc[i][9] = fmaf(kC.y, xv, acc[i][9]);
        }
        const float nw = xs[ph(ub + DDEP - 1 - d)];
        wn[3] = wn[2]; wn[2] = wn[1]; wn[1] = wn[0]; wn[0] = nw;
    }

    // transpose via LDS (stride 11), then fully-coalesced float4 stores
    #pragma unroll
    for (int i = 0; i < 4; ++i)
        #pragma unroll
        for (int o = 0; o < OUTD; ++o)
            yb[(ub + i) * 11 + o] = acc[i][o];
    __syncthreads();

    float* yg = y + ((size_t)b * TLEN + t0) * OUTD;
    #pragma unroll
    for (int pass = 0; pass < 10; ++pass) {
        const int l = (pass * NTHR + tid) * 4;
        float4 v;
        v.x = yb[l     + (l    ) / 10];
        v.y = yb[l + 1 + (l + 1) / 10];
        v.z = yb[l + 2 + (l + 2) / 10];
        v.w = yb[l + 3 + (l + 3) / 10];
        *(float4*)(yg + l) = v;
    }
}

extern "C" void kernel_launch(void* const* d_in, const int* in_sizes, int n_in,
                              void* d_out, int out_size, void* d_ws, size_t ws_size,
                              hipStream_t stream)
{
    const float* x  = (const float*)d_in[0];   // (64, 8192)
    const float* w1 = (const float*)d_in[1];   // (256, 1) contiguous
    const float* W2 = (const float*)d_in[2];   // (256, 256)
    const float* W3 = (const float*)d_in[3];   // (10, 256)
    float* y  = (float*)d_out;
    float* Kb = (float*)d_ws;                  // 120 floats

    fused_rnn_kernel<<<NBLK, dim3(NTHR), 0, stream>>>(x, w1, W2, W3, y, Kb);
}